// Round 6
// baseline (142.697 us; speedup 1.0000x reference)
//
#include <hip/hip_runtime.h>
#include <math.h>

// Problem constants: B=64, H=192, W=192, STRIDE=8, EPS=1e-7.
// All geometry in STRIDE units: the grid-cell center (cx,cy) cancels out of
// every CIoU term; the stride factor 8 cancels in all ratios (epsilons
// rescaled: union/c2 eps /64, atan-denominator eps /8).
#define EPS_F 1e-7f
#define PI_2_F 1.57079632679489662f

constexpr int kHW4    = (192 * 192) / 4;   // 9216 float4-groups per (b,ch) plane
constexpr int kTotal4 = 64 * kHW4;         // 589824
constexpr int kHalf4  = kTotal4 / 2;       // 294912
constexpr int kThreads = 256;
constexpr int kBlocks  = kHalf4 / kThreads; // 1152

// Fast reciprocal: v_rcp_f32, ~1 ulp — far inside the 1.56e-2 tolerance.
__device__ __forceinline__ float frcp(float x) { return __builtin_amdgcn_rcpf(x); }

// atan(w / h) for w >= 0, h > 0, branch-free. Range-reduce via min/max so
// z = min/max is in [0,1]; degree-11 odd minimax poly, max err ~1e-5 rad.
__device__ __forceinline__ float fast_atan_ratio(float w, float h)
{
    float num = fminf(w, h);
    float den = fmaxf(w, h);
    float z   = num * frcp(den);
    float z2  = z * z;
    float p = fmaf(z2, -0.0117212f,  0.05265332f);
    p = fmaf(z2, p, -0.11643287f);
    p = fmaf(z2, p,  0.19354346f);
    p = fmaf(z2, p, -0.33262347f);
    p = fmaf(z2, p,  0.99997726f);
    p = z * p;
    return (w > h) ? (PI_2_F - p) : p;
}

// CIoU contribution of one element, all in stride units.
__device__ __forceinline__ void ciou_elem(
    float pl, float pt, float pr, float pb,
    float tl, float tt, float tr, float tb,
    int m_i, float& ls, float& ms)
{
    const float EPS_U = EPS_F * (1.0f / 64.0f); // eps / stride^2
    const float EPS_H = EPS_F * 0.125f;         // eps / stride
    const float FOUR_OVER_PI2 = 0.40528473456935109f;
    const float ONEP = 1.0f + EPS_F;

    float mnl = fminf(pl, tl), mnr = fminf(pr, tr);
    float mnt = fminf(pt, tt), mnb = fminf(pb, tb);
    float mxl = fmaxf(pl, tl), mxr = fmaxf(pr, tr);
    float mxt = fmaxf(pt, tt), mxb = fmaxf(pb, tb);

    float w1 = pl + pr, h1 = pt + pb;      // pred w,h
    float w2 = tl + tr, h2 = tt + tb;      // target w,h
    float iw = mnl + mnr, ih = mnt + mnb;  // intersection (>=0)
    float cw = mxl + mxr, ch = mxt + mxb;  // enclosing box

    float inter = iw * ih;
    float uni   = fmaf(w1, h1, fmaf(w2, h2, EPS_U - inter));
    float iou   = inter * frcp(uni);

    float dx = (pl - pr) + (tr - tl);      // 2 * center delta (squared below)
    float dy = (pt - pb) + (tb - tt);
    float d2 = fmaf(dx, dx, dy * dy);
    float cc = fmaf(cw, cw, fmaf(ch, ch, EPS_U));
    float rr = (0.25f * d2) * frcp(cc);    // rho2 / c2

    float dv = fast_atan_ratio(w2, h2 + EPS_H) - fast_atan_ratio(w1, h1 + EPS_H);
    float v  = (FOUR_OVER_PI2 * dv) * dv;
    float av = (v * v) * frcp((v - iou) + ONEP); // alpha * v

    float ciou = (iou - rr) - av;
    bool mm = (m_i != 0);
    ls += mm ? (1.0f - ciou) : 0.0f;
    ms += mm ? 1.0f : 0.0f;
}

__device__ __forceinline__ void ciou_group(
    const float4& pl4, const float4& pt4, const float4& pr4, const float4& pb4,
    const float4& tl4, const float4& tt4, const float4& tr4, const float4& tb4,
    const int4& mk4, float& ls, float& ms)
{
    ciou_elem(pl4.x, pt4.x, pr4.x, pb4.x, tl4.x, tt4.x, tr4.x, tb4.x, mk4.x, ls, ms);
    ciou_elem(pl4.y, pt4.y, pr4.y, pb4.y, tl4.y, tt4.y, tr4.y, tb4.y, mk4.y, ls, ms);
    ciou_elem(pl4.z, pt4.z, pr4.z, pb4.z, tl4.z, tt4.z, tr4.z, tb4.z, mk4.z, ls, ms);
    ciou_elem(pl4.w, pt4.w, pr4.w, pb4.w, tl4.w, tt4.w, tr4.w, tb4.w, mk4.w, ls, ms);
}

// Fused single kernel. Body identical to R5 (2 far-split float4-groups,
// all 18 loads pinned live via empty asm). Tail: FENCE-FREE last-block
// finish — atomicAdd partials (device-scope, serialized at the L2 atomic
// unit), s_waitcnt vmcnt(0) to guarantee this block's adds committed,
// THEN the ticket atomic. No __threadfence (R3/R4's suspected 3x cost:
// device-scope release -> cross-XCD cache maintenance per block).
__global__ __launch_bounds__(256) void ciou_loss_kernel(
    const float4* __restrict__ pred, const float4* __restrict__ tgt,
    const int4* __restrict__ mask, float* __restrict__ ws,
    float* __restrict__ out)
{
    int tid = blockIdx.x * kThreads + threadIdx.x;
    int ia  = tid;
    int ib  = tid + kHalf4;

    int ba = ia / kHW4;               // compile-time divisor -> magic mul
    int pa = ia - ba * kHW4;
    int bb = ib / kHW4;
    int pb = ib - bb * kHW4;

    size_t basea = (size_t)ba * (4 * kHW4) + (size_t)pa;
    size_t baseb = (size_t)bb * (4 * kHW4) + (size_t)pb;

    // ---- issue all 18 loads ----
    float4 pla = pred[basea];
    float4 pta = pred[basea + kHW4];
    float4 pra = pred[basea + 2 * kHW4];
    float4 pba = pred[basea + 3 * kHW4];
    float4 tla = tgt[basea];
    float4 tta = tgt[basea + kHW4];
    float4 tra = tgt[basea + 2 * kHW4];
    float4 tba = tgt[basea + 3 * kHW4];
    int4   mka = mask[ia];

    float4 plb = pred[baseb];
    float4 ptb = pred[baseb + kHW4];
    float4 prb = pred[baseb + 2 * kHW4];
    float4 pbb = pred[baseb + 3 * kHW4];
    float4 tlb = tgt[baseb];
    float4 ttb = tgt[baseb + kHW4];
    float4 trb = tgt[baseb + 2 * kHW4];
    float4 tbb = tgt[baseb + 3 * kHW4];
    int4   mkb = mask[ib];

    // ---- pin all 18 loads live here: defeats register-pressure load sinking ----
    asm volatile("" ::
        "v"(pla.x), "v"(pta.x), "v"(pra.x), "v"(pba.x),
        "v"(tla.x), "v"(tta.x), "v"(tra.x), "v"(tba.x), "v"(mka.x),
        "v"(plb.x), "v"(ptb.x), "v"(prb.x), "v"(pbb.x),
        "v"(tlb.x), "v"(ttb.x), "v"(trb.x), "v"(tbb.x), "v"(mkb.x));

    float ls = 0.0f, ms = 0.0f;
    ciou_group(pla, pta, pra, pba, tla, tta, tra, tba, mka, ls, ms);
    ciou_group(plb, ptb, prb, pbb, tlb, ttb, trb, tbb, mkb, ls, ms);

    // wave-64 reduction
    #pragma unroll
    for (int off = 32; off > 0; off >>= 1) {
        ls += __shfl_down(ls, off, 64);
        ms += __shfl_down(ms, off, 64);
    }
    __shared__ float s_l[4];
    __shared__ float s_m[4];
    int wave = threadIdx.x >> 6;
    int lane = threadIdx.x & 63;
    if (lane == 0) { s_l[wave] = ls; s_m[wave] = ms; }
    __syncthreads();
    if (threadIdx.x == 0) {
        float bls = s_l[0] + s_l[1] + s_l[2] + s_l[3];
        float bms = s_m[0] + s_m[1] + s_m[2] + s_m[3];
        atomicAdd(&ws[0], bls);
        atomicAdd(&ws[1], bms);
        // Ensure THIS block's two float atomics committed at the coherence
        // point before taking a ticket. vmcnt covers global atomics; far
        // cheaper than __threadfence's cross-XCD cache maintenance.
        asm volatile("s_waitcnt vmcnt(0)" ::: "memory");
        unsigned* cnt = (unsigned*)&ws[2];
        unsigned old = atomicAdd(cnt, 1u);
        if (old == (unsigned)(kBlocks - 1)) {  // last block to finish
            float tls = atomicAdd(&ws[0], 0.0f);   // coherent read via atomic unit
            float tms = atomicAdd(&ws[1], 0.0f);
            out[0] = tls / fmaxf(tms, 1.0f);
        }
    }
}

extern "C" void kernel_launch(void* const* d_in, const int* in_sizes, int n_in,
                              void* d_out, int out_size, void* d_ws, size_t ws_size,
                              hipStream_t stream) {
    const float4* pred = (const float4*)d_in[0];
    const float4* tgt  = (const float4*)d_in[1];
    const int4*   mask = (const int4*)d_in[2];
    float* out = (float*)d_out;
    float* ws  = (float*)d_ws;

    // zero {loss-acc, mask-acc, counter, pad} — stream-ordered, capturable
    hipMemsetAsync(ws, 0, 16, stream);
    ciou_loss_kernel<<<kBlocks, kThreads, 0, stream>>>(pred, tgt, mask, ws, out);
}

// Round 7
// 105.897 us; speedup vs baseline: 1.3475x; 1.3475x over previous
//
#include <hip/hip_runtime.h>
#include <math.h>

// Problem constants: B=64, H=192, W=192, STRIDE=8, EPS=1e-7.
// All geometry in STRIDE units: the grid-cell center (cx,cy) cancels out of
// every CIoU term; the stride factor 8 cancels in all ratios (epsilons
// rescaled: union/c2 eps /64, atan-denominator eps /8).
//
// SESSION VERDICT (R0-R6): two-kernel structure at ~106.1 us is the floor.
//   - total = 82.4 us harness poison fills (2 x 256 MiB, fixed) + ~20 us
//     ciou slice + ~3 us reduce/gaps.
//   - ciou slice invariant (+-0.15 us) to: loads/thread 9 vs 18, asm-pinned
//     MLP, -30% VALU body, grid shape => bandwidth-bound on the post-poison
//     cold L3/fabric path (85 MB @ ~5-6 TB/s + ramp), not latency-bound.
//   - fused single-kernel + atomic tail: REGRESSES +30-45 us (R3/R4/R6,
//     replicated). Compiler drops to VGPR=32-44, splits/sinks the staging
//     loads into serial chains; do not re-attempt.
#define EPS_F 1e-7f
#define PI_2_F 1.57079632679489662f

constexpr int kHW4    = (192 * 192) / 4;   // 9216 float4-groups per (b,ch) plane
constexpr int kTotal4 = 64 * kHW4;         // 589824
constexpr int kHalf4  = kTotal4 / 2;       // 294912
constexpr int kThreads = 256;
constexpr int kBlocks  = kHalf4 / kThreads; // 1152

// Fast reciprocal: v_rcp_f32, ~1 ulp — far inside the 1.56e-2 tolerance.
__device__ __forceinline__ float frcp(float x) { return __builtin_amdgcn_rcpf(x); }

// atan(w / h) for w >= 0, h > 0, branch-free. Range-reduce via min/max so
// z = min/max is in [0,1]; degree-11 odd minimax poly, max err ~1e-5 rad.
__device__ __forceinline__ float fast_atan_ratio(float w, float h)
{
    float num = fminf(w, h);
    float den = fmaxf(w, h);
    float z   = num * frcp(den);
    float z2  = z * z;
    float p = fmaf(z2, -0.0117212f,  0.05265332f);
    p = fmaf(z2, p, -0.11643287f);
    p = fmaf(z2, p,  0.19354346f);
    p = fmaf(z2, p, -0.33262347f);
    p = fmaf(z2, p,  0.99997726f);
    p = z * p;
    return (w > h) ? (PI_2_F - p) : p;
}

// CIoU contribution of one element, all in stride units.
__device__ __forceinline__ void ciou_elem(
    float pl, float pt, float pr, float pb,
    float tl, float tt, float tr, float tb,
    int m_i, float& ls, float& ms)
{
    const float EPS_U = EPS_F * (1.0f / 64.0f); // eps / stride^2
    const float EPS_H = EPS_F * 0.125f;         // eps / stride
    const float FOUR_OVER_PI2 = 0.40528473456935109f;
    const float ONEP = 1.0f + EPS_F;

    float mnl = fminf(pl, tl), mnr = fminf(pr, tr);
    float mnt = fminf(pt, tt), mnb = fminf(pb, tb);
    float mxl = fmaxf(pl, tl), mxr = fmaxf(pr, tr);
    float mxt = fmaxf(pt, tt), mxb = fmaxf(pb, tb);

    float w1 = pl + pr, h1 = pt + pb;      // pred w,h
    float w2 = tl + tr, h2 = tt + tb;      // target w,h
    float iw = mnl + mnr, ih = mnt + mnb;  // intersection (>=0)
    float cw = mxl + mxr, ch = mxt + mxb;  // enclosing box

    float inter = iw * ih;
    float uni   = fmaf(w1, h1, fmaf(w2, h2, EPS_U - inter));
    float iou   = inter * frcp(uni);

    float dx = (pl - pr) + (tr - tl);      // 2 * center delta (squared below)
    float dy = (pt - pb) + (tb - tt);
    float d2 = fmaf(dx, dx, dy * dy);
    float cc = fmaf(cw, cw, fmaf(ch, ch, EPS_U));
    float rr = (0.25f * d2) * frcp(cc);    // rho2 / c2

    float dv = fast_atan_ratio(w2, h2 + EPS_H) - fast_atan_ratio(w1, h1 + EPS_H);
    float v  = (FOUR_OVER_PI2 * dv) * dv;
    float av = (v * v) * frcp((v - iou) + ONEP); // alpha * v

    float ciou = (iou - rr) - av;
    bool mm = (m_i != 0);
    ls += mm ? (1.0f - ciou) : 0.0f;
    ms += mm ? 1.0f : 0.0f;
}

__device__ __forceinline__ void ciou_group(
    const float4& pl4, const float4& pt4, const float4& pr4, const float4& pb4,
    const float4& tl4, const float4& tt4, const float4& tr4, const float4& tb4,
    const int4& mk4, float& ls, float& ms)
{
    ciou_elem(pl4.x, pt4.x, pr4.x, pb4.x, tl4.x, tt4.x, tr4.x, tb4.x, mk4.x, ls, ms);
    ciou_elem(pl4.y, pt4.y, pr4.y, pb4.y, tl4.y, tt4.y, tr4.y, tb4.y, mk4.y, ls, ms);
    ciou_elem(pl4.z, pt4.z, pr4.z, pb4.z, tl4.z, tt4.z, tr4.z, tb4.z, mk4.z, ls, ms);
    ciou_elem(pl4.w, pt4.w, pr4.w, pb4.w, tl4.w, tt4.w, tr4.w, tb4.w, mk4.w, ls, ms);
}

// Two-kernel structure (verified fastest: 106.1-106.2 us total). Each thread:
// two far-split float4-groups, all 18 x 16B loads issued before compute with
// an empty asm pinning one lane of each (keeps issue order; a dwordx4 cannot
// retire partially ahead of its .x).
__global__ __launch_bounds__(256) void ciou_loss_kernel(
    const float4* __restrict__ pred, const float4* __restrict__ tgt,
    const int4* __restrict__ mask, float2* __restrict__ parts)
{
    int tid = blockIdx.x * kThreads + threadIdx.x;
    int ia  = tid;
    int ib  = tid + kHalf4;

    int ba = ia / kHW4;               // compile-time divisor -> magic mul
    int pa = ia - ba * kHW4;
    int bb = ib / kHW4;
    int pb = ib - bb * kHW4;

    size_t basea = (size_t)ba * (4 * kHW4) + (size_t)pa;
    size_t baseb = (size_t)bb * (4 * kHW4) + (size_t)pb;

    // ---- issue all 18 loads ----
    float4 pla = pred[basea];
    float4 pta = pred[basea + kHW4];
    float4 pra = pred[basea + 2 * kHW4];
    float4 pba = pred[basea + 3 * kHW4];
    float4 tla = tgt[basea];
    float4 tta = tgt[basea + kHW4];
    float4 tra = tgt[basea + 2 * kHW4];
    float4 tba = tgt[basea + 3 * kHW4];
    int4   mka = mask[ia];

    float4 plb = pred[baseb];
    float4 ptb = pred[baseb + kHW4];
    float4 prb = pred[baseb + 2 * kHW4];
    float4 pbb = pred[baseb + 3 * kHW4];
    float4 tlb = tgt[baseb];
    float4 ttb = tgt[baseb + kHW4];
    float4 trb = tgt[baseb + 2 * kHW4];
    float4 tbb = tgt[baseb + 3 * kHW4];
    int4   mkb = mask[ib];

    // ---- pin all 18 loads live here ----
    asm volatile("" ::
        "v"(pla.x), "v"(pta.x), "v"(pra.x), "v"(pba.x),
        "v"(tla.x), "v"(tta.x), "v"(tra.x), "v"(tba.x), "v"(mka.x),
        "v"(plb.x), "v"(ptb.x), "v"(prb.x), "v"(pbb.x),
        "v"(tlb.x), "v"(ttb.x), "v"(trb.x), "v"(tbb.x), "v"(mkb.x));

    float ls = 0.0f, ms = 0.0f;
    ciou_group(pla, pta, pra, pba, tla, tta, tra, tba, mka, ls, ms);
    ciou_group(plb, ptb, prb, pbb, tlb, ttb, trb, tbb, mkb, ls, ms);

    // wave-64 reduction
    #pragma unroll
    for (int off = 32; off > 0; off >>= 1) {
        ls += __shfl_down(ls, off, 64);
        ms += __shfl_down(ms, off, 64);
    }
    __shared__ float s_l[4];
    __shared__ float s_m[4];
    int wave = threadIdx.x >> 6;
    int lane = threadIdx.x & 63;
    if (lane == 0) { s_l[wave] = ls; s_m[wave] = ms; }
    __syncthreads();
    if (threadIdx.x == 0) {
        float2 p;
        p.x = s_l[0] + s_l[1] + s_l[2] + s_l[3];
        p.y = s_m[0] + s_m[1] + s_m[2] + s_m[3];
        parts[blockIdx.x] = p;
    }
}

__global__ __launch_bounds__(256) void reduce_kernel(
    const float2* __restrict__ parts, float* __restrict__ out)
{
    float ls = 0.0f, ms = 0.0f;
    for (int i = threadIdx.x; i < kBlocks; i += kThreads) {
        float2 p = parts[i];
        ls += p.x;
        ms += p.y;
    }
    #pragma unroll
    for (int off = 32; off > 0; off >>= 1) {
        ls += __shfl_down(ls, off, 64);
        ms += __shfl_down(ms, off, 64);
    }
    __shared__ float s_l[4];
    __shared__ float s_m[4];
    int wave = threadIdx.x >> 6;
    int lane = threadIdx.x & 63;
    if (lane == 0) { s_l[wave] = ls; s_m[wave] = ms; }
    __syncthreads();
    if (threadIdx.x == 0) {
        float tls = s_l[0] + s_l[1] + s_l[2] + s_l[3];
        float tms = s_m[0] + s_m[1] + s_m[2] + s_m[3];
        out[0] = tls / fmaxf(tms, 1.0f);
    }
}

extern "C" void kernel_launch(void* const* d_in, const int* in_sizes, int n_in,
                              void* d_out, int out_size, void* d_ws, size_t ws_size,
                              hipStream_t stream) {
    const float4* pred = (const float4*)d_in[0];
    const float4* tgt  = (const float4*)d_in[1];
    const int4*   mask = (const int4*)d_in[2];
    float* out  = (float*)d_out;
    float2* parts = (float2*)d_ws;

    ciou_loss_kernel<<<kBlocks, kThreads, 0, stream>>>(pred, tgt, mask, parts);
    reduce_kernel<<<1, kThreads, 0, stream>>>(parts, out);
}